// Round 6
// baseline (1226.048 us; speedup 1.0000x reference)
//
#include <hip/hip_runtime.h>

#define NNODE 500000
#define NEDGE 8000000
#define NBUCK 489              // partition buckets: dst >> 10
#define BCAP  18000            // per-bucket record capacity
#define SENT  0xFFFFFFFFu      // sentinel: src field >= NNODE -> skipped

#define PCAP      32
#define PTHREADS  512
#define PBLOCKS   256
#define EPB       (NEDGE / PBLOCKS)   // 31250

#define NABLK 977              // ceil(NNODE/512) aggregate blocks (2 per bucket)
#define ASTRIDE 17             // padded LDS node stride (bank-conflict break)
#define NCHUNK 8               // src phase chunks: 65536 nodes = 4 MB of y = one XCD L2
#define CHSH 16

// ---------------------------------------------------------------------------
// setup: Wf[16][32] = W_gcn[16][48] @ W1[48][32], zero bucket cursors
// ---------------------------------------------------------------------------
__global__ void setup_kernel(const float* __restrict__ Wg,
                             const float* __restrict__ W1,
                             float* __restrict__ Wf,
                             int* __restrict__ gcursor) {
    int t = threadIdx.x;
    int r = t >> 5;
    int c = t & 31;
    float s = 0.f;
    #pragma unroll
    for (int k = 0; k < 48; ++k) s += Wg[r * 48 + k] * W1[k * 32 + c];
    Wf[t] = s;
    if (t < NBUCK) gcursor[t] = 0;
}

// ---------------------------------------------------------------------------
// partition: edges -> per-bucket records, LDS-staged, 64B-granule flushes
// record = (dst & 1023) << 19 | src
// ---------------------------------------------------------------------------
__global__ __launch_bounds__(PTHREADS) void partition_kernel(
        const int* __restrict__ src, const int* __restrict__ dst,
        int* __restrict__ gcursor, unsigned* __restrict__ bdata) {
    __shared__ unsigned stage[NBUCK * PCAP];   // 62592 B
    __shared__ int lcnt[NBUCK];
    int tid = threadIdx.x;
    for (int b = tid; b < NBUCK; b += PTHREADS) lcnt[b] = 0;
    __syncthreads();

    int base = blockIdx.x * EPB;
    int nrounds = (EPB + PTHREADS - 1) / PTHREADS;
    for (int r = 0; r < nrounds; ++r) {
        int e = base + r * PTHREADS + tid;
        if (e < base + EPB) {
            int s = src[e];
            int d = dst[e];
            unsigned rec = ((unsigned)(d & 1023) << 19) | (unsigned)s;
            int b = d >> 10;
            int pos = atomicAdd(&lcnt[b], 1);
            if (pos < PCAP) {
                stage[b * PCAP + pos] = rec;
            } else {
                int gp = atomicAdd(&gcursor[b], 4);
                if (gp + 4 <= BCAP) {
                    unsigned* o = &bdata[(size_t)b * BCAP + gp];
                    o[0] = rec; o[1] = SENT; o[2] = SENT; o[3] = SENT;
                }
            }
        }
        __syncthreads();
        if (tid < NBUCK) {
            int b = tid;
            int k = lcnt[b];
            if (k > PCAP) k = PCAP;
            int nf = k & ~15;
            if (nf > 0) {
                int gp = atomicAdd(&gcursor[b], nf);
                if (gp + nf <= BCAP) {
                    unsigned* o = &bdata[(size_t)b * BCAP + gp];
                    #pragma unroll
                    for (int q = 0; q < 2; ++q) {
                        if (q * 16 < nf) {
                            uint4 v0 = *(const uint4*)&stage[b * PCAP + q * 16];
                            uint4 v1 = *(const uint4*)&stage[b * PCAP + q * 16 + 4];
                            uint4 v2 = *(const uint4*)&stage[b * PCAP + q * 16 + 8];
                            uint4 v3 = *(const uint4*)&stage[b * PCAP + q * 16 + 12];
                            *(uint4*)&o[q * 16]      = v0;
                            *(uint4*)&o[q * 16 + 4]  = v1;
                            *(uint4*)&o[q * 16 + 8]  = v2;
                            *(uint4*)&o[q * 16 + 12] = v3;
                        }
                    }
                }
                int rem = k - nf;
                for (int q = 0; q < rem; ++q)
                    stage[b * PCAP + q] = stage[b * PCAP + nf + q];
                lcnt[b] = rem;
            }
        }
        __syncthreads();
    }
    if (tid < NBUCK) {
        int b = tid;
        int k = lcnt[b];
        if (k > PCAP) k = PCAP;
        if (k > 0) {
            int kp = (k + 3) & ~3;
            for (int q = k; q < kp; ++q) stage[b * PCAP + q] = SENT;
            int gp = atomicAdd(&gcursor[b], kp);
            if (gp + kp <= BCAP) {
                unsigned* o = &bdata[(size_t)b * BCAP + gp];
                for (int q = 0; q < kp; q += 4)
                    *(uint4*)&o[q] = *(const uint4*)&stage[b * PCAP + q];
            }
        }
    }
}

// ---------------------------------------------------------------------------
// per-bucket degree histogram -> dinv = rsqrt(deg + 1)
// ---------------------------------------------------------------------------
__global__ __launch_bounds__(256) void dinv_kernel(
        const int* __restrict__ gcursor, const unsigned* __restrict__ bdata,
        float* __restrict__ dinv) {
    __shared__ int ldeg[1024];
    int b = blockIdx.x, tid = threadIdx.x;
    for (int k = tid; k < 1024; k += 256) ldeg[k] = 0;
    __syncthreads();
    int n = gcursor[b];
    if (n > BCAP) n = BCAP;
    const unsigned* bd = bdata + (size_t)b * BCAP;
    for (int j = tid; j < n; j += 256) {
        unsigned rec = bd[j];
        if ((rec & 0x7FFFFu) < NNODE) atomicAdd(&ldeg[rec >> 19], 1);
    }
    __syncthreads();
    int base = b << 10;
    for (int k = tid; k < 1024; k += 256) {
        int i = base + k;
        if (i < NNODE) dinv[i] = rsqrtf((float)(ldeg[k] + 1));
    }
}

// ---------------------------------------------------------------------------
// y[i][c] = xx[i][c] * dinv[i]   (float4 per thread)
// ---------------------------------------------------------------------------
__global__ __launch_bounds__(256) void y_kernel(
        const float* __restrict__ xx, const float* __restrict__ dinv,
        float* __restrict__ y) {
    int t = blockIdx.x * 256 + threadIdx.x;
    if (t < NNODE * 4) {
        float di = dinv[t >> 2];
        float4 v = ((const float4*)xx)[t];
        v.x *= di; v.y *= di; v.z *= di; v.w *= di;
        ((float4*)y)[t] = v;
    }
}

// ---------------------------------------------------------------------------
// fused aggregate + epilogue, PHASE-TILED over src chunks.
// Block b owns nodes [b*512, b*512+512), reads parent bucket (b>>1), filters
// by half. 8 phases: phase p gathers only src in [p<<16, (p+1)<<16) so the
// random y reads stay inside a 4 MB window == one XCD L2. Record list is
// 64 KB -> L2-resident across the 8 re-scans.
// ---------------------------------------------------------------------------
__global__ __launch_bounds__(512, 6) void agg_final_kernel(
        const int* __restrict__ gcursor, const unsigned* __restrict__ bdata,
        const float* __restrict__ xx, const float* __restrict__ y,
        const float* __restrict__ dinv, const float* __restrict__ Wf,
        const float* __restrict__ b1, const float* __restrict__ W2,
        const float* __restrict__ b2, float* __restrict__ out) {
    __shared__ float acc[512 * ASTRIDE];     // 34816 B
    __shared__ float sWf[512];
    __shared__ float sW2[512];
    __shared__ float sb1[32];
    __shared__ float sb2[16];
    int tid = threadIdx.x;
    int b = blockIdx.x;
    int pb = b >> 1;
    int hbase = (b & 1) << 9;                // 0 or 512

    for (int k = tid; k < 512 * ASTRIDE; k += 512) acc[k] = 0.f;
    sWf[tid] = Wf[tid];
    sW2[tid] = W2[tid];
    if (tid < 32) sb1[tid] = b1[tid];
    if (tid < 16) sb2[tid] = b2[tid];
    __syncthreads();

    int n = gcursor[pb];
    if (n > BCAP) n = BCAP;
    const unsigned* bd = bdata + (size_t)pb * BCAP;
    int q = tid >> 2;          // quad 0..127
    int s = tid & 3;           // 16B slice within row

    for (int p = 0; p < NCHUNK; ++p) {
        unsigned lo = (unsigned)p << CHSH;
        unsigned hi = lo + (1u << CHSH);
        int j = q;
        for (; j + 128 < n; j += 256) {
            unsigned r0 = bd[j];
            unsigned r1 = bd[j + 128];
            unsigned s0 = r0 & 0x7FFFFu, s1 = r1 & 0x7FFFFu;
            int d0 = (int)(r0 >> 19) - hbase;
            int d1 = (int)(r1 >> 19) - hbase;
            bool p0 = (s0 >= lo) & (s0 < hi) & (s0 < NNODE) & ((unsigned)d0 < 512u);
            bool p1 = (s1 >= lo) & (s1 < hi) & (s1 < NNODE) & ((unsigned)d1 < 512u);
            float4 v0, v1;
            if (p0) v0 = *(const float4*)&y[(size_t)s0 * 16 + s * 4];
            if (p1) v1 = *(const float4*)&y[(size_t)s1 * 16 + s * 4];
            if (p0) {
                float* a0 = &acc[d0 * ASTRIDE + s * 4];
                atomicAdd(&a0[0], v0.x); atomicAdd(&a0[1], v0.y);
                atomicAdd(&a0[2], v0.z); atomicAdd(&a0[3], v0.w);
            }
            if (p1) {
                float* a1 = &acc[d1 * ASTRIDE + s * 4];
                atomicAdd(&a1[0], v1.x); atomicAdd(&a1[1], v1.y);
                atomicAdd(&a1[2], v1.z); atomicAdd(&a1[3], v1.w);
            }
        }
        for (; j < n; j += 128) {
            unsigned r0 = bd[j];
            unsigned s0 = r0 & 0x7FFFFu;
            int d0 = (int)(r0 >> 19) - hbase;
            if ((s0 >= lo) & (s0 < hi) & (s0 < NNODE) & ((unsigned)d0 < 512u)) {
                float4 v0 = *(const float4*)&y[(size_t)s0 * 16 + s * 4];
                float* a0 = &acc[d0 * ASTRIDE + s * 4];
                atomicAdd(&a0[0], v0.x); atomicAdd(&a0[1], v0.y);
                atomicAdd(&a0[2], v0.z); atomicAdd(&a0[3], v0.w);
            }
        }
    }
    __syncthreads();

    // epilogue: one node per thread
    int i = b * 512 + tid;
    if (i >= NNODE) return;
    float di = dinv[i];
    const float4* xx4 = (const float4*)(xx + (size_t)i * 16);
    float x[16], a[16];
    #pragma unroll
    for (int qq = 0; qq < 4; ++qq) {
        float4 xv = xx4[qq];
        x[4 * qq + 0] = xv.x; x[4 * qq + 1] = xv.y;
        x[4 * qq + 2] = xv.z; x[4 * qq + 3] = xv.w;
    }
    #pragma unroll
    for (int c = 0; c < 16; ++c)
        a[c] = di * (acc[tid * ASTRIDE + c] + x[c] * di);

    float tacc[32];
    #pragma unroll
    for (int jj = 0; jj < 32; ++jj) tacc[jj] = sb1[jj];
    #pragma unroll
    for (int c = 0; c < 16; ++c) {
        float av = a[c];
        #pragma unroll
        for (int jj = 0; jj < 32; ++jj) tacc[jj] += av * sWf[c * 32 + jj];
    }
    #pragma unroll
    for (int jj = 0; jj < 32; ++jj) tacc[jj] = fmaxf(tacc[jj], 0.f);

    float u[16];
    #pragma unroll
    for (int c = 0; c < 16; ++c) u[c] = sb2[c];
    #pragma unroll
    for (int jj = 0; jj < 32; ++jj) {
        float tv = tacc[jj];
        #pragma unroll
        for (int c = 0; c < 16; ++c) u[c] += tv * sW2[jj * 16 + c];
    }

    float4* o4 = (float4*)(out + (size_t)i * 16);
    #pragma unroll
    for (int qq = 0; qq < 4; ++qq) {
        o4[qq] = make_float4(x[4 * qq + 0] + u[4 * qq + 0],
                             x[4 * qq + 1] + u[4 * qq + 1],
                             x[4 * qq + 2] + u[4 * qq + 2],
                             x[4 * qq + 3] + u[4 * qq + 3]);
    }
}

extern "C" void kernel_launch(void* const* d_in, const int* in_sizes, int n_in,
                              void* d_out, int out_size, void* d_ws, size_t ws_size,
                              hipStream_t stream) {
    const float* xx   = (const float*)d_in[0];
    const int*   edge = (const int*)d_in[1];
    const float* Wg   = (const float*)d_in[2];
    const float* W1   = (const float*)d_in[3];
    const float* b1   = (const float*)d_in[4];
    const float* W2   = (const float*)d_in[5];
    const float* b2   = (const float*)d_in[6];
    float* out = (float*)d_out;

    const int* srcI = edge;
    const int* dstI = edge + NEDGE;

    // ws layout (4B elems):
    //   gcursor[512] | Wf[512] | dinv[N] | y[16N] | bdata[NBUCK*BCAP]
    int*      ws      = (int*)d_ws;
    int*      gcursor = ws;
    float*    Wf      = (float*)(ws + 512);
    float*    dinv    = (float*)(ws + 1024);
    float*    y       = (float*)(ws + 1024 + NNODE);
    unsigned* bdata   = (unsigned*)(ws + 1024 + NNODE + 16 * (size_t)NNODE);

    hipLaunchKernelGGL(setup_kernel, dim3(1), dim3(512), 0, stream,
                       Wg, W1, Wf, gcursor);

    hipLaunchKernelGGL(partition_kernel, dim3(PBLOCKS), dim3(PTHREADS), 0, stream,
                       srcI, dstI, gcursor, bdata);

    hipLaunchKernelGGL(dinv_kernel, dim3(NBUCK), dim3(256), 0, stream,
                       gcursor, bdata, dinv);

    hipLaunchKernelGGL(y_kernel, dim3((NNODE * 4 + 255) / 256), dim3(256), 0, stream,
                       xx, dinv, y);

    hipLaunchKernelGGL(agg_final_kernel, dim3(NABLK), dim3(512), 0, stream,
                       gcursor, bdata, xx, y, dinv, Wf, b1, W2, b2, out);
}